// Round 2
// baseline (1136.682 us; speedup 1.0000x reference)
//
#include <hip/hip_runtime.h>

static constexpr int Bn = 8, Dn = 512, Hn = 64, Wn = 64, Kn = 1024;
static constexpr int HW = Hn * Wn;            // 4096
static constexpr int NPIX = Bn * HW;          // 32768
static constexpr size_t OFF_LOSS = (size_t)Bn * Dn * HW;          // 16777216
static constexpr size_t OFF_PROB = OFF_LOSS + 1;                   // 16777217
static constexpr size_t OFF_IDX  = OFF_PROB + (size_t)NPIX * Kn;   // 50331649
static constexpr size_t OFF_PPRB = OFF_IDX + NPIX;                 // 50364417

// ---- numpy pairwise-sum replica for n=512 f32 row of squares ----
// pairwise(512) = (P(0:256)) + (P(256:512)); P(256) = P(128)+P(128)
// 128-block: baseline-SIMD (vstep=4): 8 vector accs r[k][j], j=0..3:
//   r[k][j] = ((y[4k+j] + y[32+4k+j]) + y[64+4k+j]) + y[96+4k+j]
//   L[j] = ((r0+r1)+(r2+r3)) + ((r4+r5)+(r6+r7))
//   B = (L0+L1) + (L2+L3)          (SSE3 hadd npyv_sum)
// total = (B0+B1) + (B2+B3)
__device__ float np_pairwise_sq512(const float* __restrict__ base, int stride) {
  float B[4];
#pragma unroll
  for (int blk = 0; blk < 4; blk++) {
    const float* a = base + (size_t)blk * 128 * stride;
    float r[8][4];
#pragma unroll
    for (int k = 0; k < 8; k++)
#pragma unroll
      for (int j = 0; j < 4; j++) {
        float x = a[(size_t)(4 * k + j) * stride];
        r[k][j] = __fmul_rn(x, x);
      }
#pragma unroll
    for (int i = 32; i < 128; i += 32)
#pragma unroll
      for (int k = 0; k < 8; k++)
#pragma unroll
        for (int j = 0; j < 4; j++) {
          float x = a[(size_t)(i + 4 * k + j) * stride];
          r[k][j] = __fadd_rn(r[k][j], __fmul_rn(x, x));
        }
    float L[4];
#pragma unroll
    for (int j = 0; j < 4; j++) {
      float t01 = __fadd_rn(r[0][j], r[1][j]);
      float t23 = __fadd_rn(r[2][j], r[3][j]);
      float t45 = __fadd_rn(r[4][j], r[5][j]);
      float t67 = __fadd_rn(r[6][j], r[7][j]);
      L[j] = __fadd_rn(__fadd_rn(t01, t23), __fadd_rn(t45, t67));
    }
    B[blk] = __fadd_rn(__fadd_rn(L[0], L[1]), __fadd_rn(L[2], L[3]));
  }
  return __fadd_rn(__fadd_rn(B[0], B[1]), __fadd_rn(B[2], B[3]));
}

// ---------------- K0: row squared-norms (np-replicated) ----------------
// gid < 32768: z row; < 65536: z_pos row; else codebook row
__global__ __launch_bounds__(256) void k_sq(const float* __restrict__ Z,
                                            const float* __restrict__ ZP,
                                            const float* __restrict__ CB,
                                            float* __restrict__ xxZ,
                                            float* __restrict__ xxP,
                                            float* __restrict__ cb2) {
  int gid = blockIdx.x * 256 + threadIdx.x;
  if (gid < NPIX) {
    int b = gid >> 12, hw = gid & 4095;
    xxZ[gid] = np_pairwise_sq512(Z + (size_t)b * Dn * HW + hw, HW);
  } else if (gid < 2 * NPIX) {
    int p = gid - NPIX;
    int b = p >> 12, hw = p & 4095;
    xxP[p] = np_pairwise_sq512(ZP + (size_t)b * Dn * HW + hw, HW);
  } else if (gid < 2 * NPIX + Kn) {
    int k = gid - 2 * NPIX;
    cb2[k] = np_pairwise_sq512(CB + (size_t)k * Dn, 1);
  }
}

// ---------------- K1: d = fl((xx + cb2) - 2*m), m = seq-fma f32 GEMM ----------------
// grid: (Kn/128, NPIX/128, 2)   block: 256
__global__ __launch_bounds__(256) void k_gemm(const float* __restrict__ Z,
                                              const float* __restrict__ ZP,
                                              const float* __restrict__ CB,
                                              const float* __restrict__ cb2,
                                              const float* __restrict__ xxZ,
                                              const float* __restrict__ xxP,
                                              float* __restrict__ out) {
  __shared__ float smem[64 * 132];            // staging (2x16x132) + epilogue (64x132)
  float* As = smem;                           // [16][132]
  float* Bs = smem + 16 * 132;                // [16][132]
  const int tk = blockIdx.x * 128;
  const int tp = blockIdx.y * 128;
  const float* A = blockIdx.z ? ZP : Z;
  const float* xx = blockIdx.z ? xxP : xxZ;
  float* S = out + (blockIdx.z ? OFF_PPRB : OFF_PROB);
  const int bb = tp >> 12, hw0 = tp & 4095;
  const float* Abase = A + (size_t)bb * Dn * HW + hw0;   // + c*HW + hw
  const float* Bbase = CB + (size_t)tk * Dn;             // + kl*Dn + c
  const int tid = threadIdx.x;
  const int tx = tid & 15, ty = tid >> 4;

  float acc[8][8] = {};
  for (int c0 = 0; c0 < Dn; c0 += 16) {
#pragma unroll
    for (int i = 0; i < 8; i++) {
      int idx = tid + i * 256;
      int cl = idx >> 7, hwl = idx & 127;
      As[cl * 132 + hwl] = Abase[(size_t)(c0 + cl) * HW + hwl];
    }
#pragma unroll
    for (int i = 0; i < 8; i++) {
      int idx = tid + i * 256;
      int cl = idx & 15, kl = idx >> 4;
      Bs[cl * 132 + kl] = Bbase[(size_t)kl * Dn + c0 + cl];
    }
    __syncthreads();
#pragma unroll
    for (int c = 0; c < 16; c++) {
      float4 a0 = *(const float4*)(As + c * 132 + tx * 4);
      float4 a1 = *(const float4*)(As + c * 132 + 64 + tx * 4);
      float4 b0 = *(const float4*)(Bs + c * 132 + ty * 4);
      float4 b1 = *(const float4*)(Bs + c * 132 + 64 + ty * 4);
      float av[8] = {a0.x, a0.y, a0.z, a0.w, a1.x, a1.y, a1.z, a1.w};
      float bv[8] = {b0.x, b0.y, b0.z, b0.w, b1.x, b1.y, b1.z, b1.w};
#pragma unroll
      for (int i = 0; i < 8; i++)
#pragma unroll
        for (int j = 0; j < 8; j++) acc[i][j] = fmaf(av[i], bv[j], acc[i][j]);
    }
    __syncthreads();
  }

  // epilogue via LDS for coalesced (scalar) stores; d replicates np f32 order:
  // T1 = fl(xx + cb2); d = fl(T1 - 2*m)
#pragma unroll
  for (int half = 0; half < 2; half++) {
    __syncthreads();
#pragma unroll
    for (int i = 0; i < 4; i++) {
      int ii = half * 4 + i;
      int r = tx * 4 + i;  // row within this 64-row half
#pragma unroll
      for (int j = 0; j < 8; j++) {
        int col = (j < 4) ? (ty * 4 + j) : (64 + ty * 4 + (j - 4));
        smem[r * 132 + col] = acc[ii][j];
      }
    }
    __syncthreads();
    for (int it = 0; it < 32; it++) {
      int idx = it * 256 + tid;
      int r = idx >> 7, col = idx & 127;
      int prow = tp + half * 64 + r;
      int kcol = tk + col;
      float m = smem[r * 132 + col];
      float T1 = __fadd_rn(xx[prow], cb2[kcol]);
      float d = __fsub_rn(T1, __fmul_rn(2.0f, m));
      S[(size_t)prow * Kn + kcol] = d;
    }
  }
}

// ---------------- K2: per-row argmin (first-index ties) + softmax ----------------
// grid: (NPIX, 2)  block: 256  -- in-place on the d rows
__global__ __launch_bounds__(256) void k_row(float* __restrict__ out,
                                             int* __restrict__ widx) {
  const int p = blockIdx.x;
  const int sel = blockIdx.y;
  float* S = out + (sel ? OFF_PPRB : OFF_PROB) + (size_t)p * Kn;
  const int t = threadIdx.x;
  __shared__ float rf[256];
  __shared__ int ri[256];

  float v[4];
#pragma unroll
  for (int i = 0; i < 4; i++) v[i] = S[t + i * 256];

  // per-thread argmin (ascending scan, strict < keeps lowest index on ties)
  float lmin = v[0];
  int lidx = t;
#pragma unroll
  for (int i = 1; i < 4; i++) {
    if (v[i] < lmin) { lmin = v[i]; lidx = t + i * 256; }
  }
  rf[t] = lmin; ri[t] = lidx;
  __syncthreads();
  for (int s = 128; s > 0; s >>= 1) {
    if (t < s) {
      float o = rf[t + s]; int oi = ri[t + s];
      if (o < rf[t] || (o == rf[t] && oi < ri[t])) { rf[t] = o; ri[t] = oi; }
    }
    __syncthreads();
  }
  const float smin = rf[0];
  const int sidx = ri[0];
  __syncthreads();

  // softmax: prob_k = exp(smin - d_k) / sum
  float e[4];
  float ls = 0.f;
#pragma unroll
  for (int i = 0; i < 4; i++) { e[i] = expf(smin - v[i]); ls += e[i]; }
  rf[t] = ls;
  __syncthreads();
  for (int s = 128; s > 0; s >>= 1) {
    if (t < s) rf[t] += rf[t + s];
    __syncthreads();
  }
  const float inv = 1.0f / rf[0];
#pragma unroll
  for (int i = 0; i < 4; i++) S[t + i * 256] = e[i] * inv;

  if (sel == 0 && t == 0) {
    out[OFF_IDX + p] = (float)sidx;
    widx[p] = sidx;
  }
}

// ---------------- K3: z_q gather + squared-error partials ----------------
__global__ __launch_bounds__(256) void k_zqloss(const float* __restrict__ Z,
                                                const float* __restrict__ CB,
                                                const int* __restrict__ widx,
                                                float* __restrict__ out,
                                                float* __restrict__ partial) {
  __shared__ float red[256];
  const int t = threadIdx.x;
  float ls = 0.f;
  const size_t base = (size_t)blockIdx.x * 4096;
#pragma unroll
  for (int i = 0; i < 16; i++) {
    size_t e = base + (size_t)i * 256 + t;
    int hw = (int)(e & 4095);
    int c = (int)((e >> 12) & 511);
    int bb = (int)(e >> 21);
    int p = (bb << 12) | hw;
    float zv = Z[e];
    float qv = CB[(size_t)widx[p] * Dn + c];
    out[e] = qv;  // straight-through z_q == codebook[idx]
    float d = zv - qv;
    ls = fmaf(d, d, ls);
  }
  red[t] = ls;
  __syncthreads();
  for (int s = 128; s > 0; s >>= 1) {
    if (t < s) red[t] += red[t + s];
    __syncthreads();
  }
  if (t == 0) partial[blockIdx.x] = red[0];
}

// ---------------- K4: finalize q_loss ----------------
__global__ __launch_bounds__(256) void k_loss(const float* __restrict__ partial,
                                              float* __restrict__ out) {
  __shared__ float red[256];
  const int t = threadIdx.x;
  float s = 0.f;
  for (int i = t; i < 4096; i += 256) s += partial[i];
  red[t] = s;
  __syncthreads();
  for (int k = 128; k > 0; k >>= 1) {
    if (t < k) red[t] += red[t + k];
    __syncthreads();
  }
  // q_loss = (1 + BETA) * mean((z - z_q)^2), BETA = 0.25
  if (t == 0) out[OFF_LOSS] = red[0] * (1.25f / 16777216.0f);
}

extern "C" void kernel_launch(void* const* d_in, const int* in_sizes, int n_in,
                              void* d_out, int out_size, void* d_ws, size_t ws_size,
                              hipStream_t stream) {
  const float* Z = (const float*)d_in[0];
  const float* ZP = (const float*)d_in[1];
  const float* CB = (const float*)d_in[2];
  float* out = (float*)d_out;
  float* cb2 = (float*)d_ws;                                       // 1024 f32
  float* xxZ = (float*)((char*)d_ws + 4096);                       // 32768 f32
  float* xxP = (float*)((char*)d_ws + 4096 + 131072);              // 32768 f32
  int* widx = (int*)((char*)d_ws + 4096 + 262144);                 // 32768 i32
  float* partial = (float*)((char*)d_ws + 4096 + 262144 + 131072); // 4096 f32

  k_sq<<<dim3((2 * NPIX + Kn + 255) / 256), 256, 0, stream>>>(Z, ZP, CB, xxZ, xxP, cb2);
  k_gemm<<<dim3(Kn / 128, NPIX / 128, 2), 256, 0, stream>>>(Z, ZP, CB, cb2, xxZ, xxP, out);
  k_row<<<dim3(NPIX, 2), 256, 0, stream>>>(out, widx);
  k_zqloss<<<dim3(4096), 256, 0, stream>>>(Z, CB, widx, out, partial);
  k_loss<<<dim3(1), 256, 0, stream>>>(partial, out);
}

// Round 3
// 668.981 us; speedup vs baseline: 1.6991x; 1.6991x over previous
//
#include <hip/hip_runtime.h>

static constexpr int Bn = 8, Dn = 512, Hn = 64, Wn = 64, Kn = 1024;
static constexpr int HW = Hn * Wn;            // 4096
static constexpr int NPIX = Bn * HW;          // 32768
static constexpr size_t OFF_LOSS = (size_t)Bn * Dn * HW;          // 16777216
static constexpr size_t OFF_PROB = OFF_LOSS + 1;                   // 16777217
static constexpr size_t OFF_IDX  = OFF_PROB + (size_t)NPIX * Kn;   // 50331649
static constexpr size_t OFF_PPRB = OFF_IDX + NPIX;                 // 50364417

typedef __attribute__((ext_vector_type(8))) short short8v;
typedef __attribute__((ext_vector_type(4))) float f32x4;

// ---- numpy pairwise-sum replica for n=512 f32 row of squares ----
__device__ float np_pairwise_sq512(const float* __restrict__ base, int stride) {
  float B[4];
#pragma unroll
  for (int blk = 0; blk < 4; blk++) {
    const float* a = base + (size_t)blk * 128 * stride;
    float r[8][4];
#pragma unroll
    for (int k = 0; k < 8; k++)
#pragma unroll
      for (int j = 0; j < 4; j++) {
        float x = a[(size_t)(4 * k + j) * stride];
        r[k][j] = __fmul_rn(x, x);
      }
#pragma unroll
    for (int i = 32; i < 128; i += 32)
#pragma unroll
      for (int k = 0; k < 8; k++)
#pragma unroll
        for (int j = 0; j < 4; j++) {
          float x = a[(size_t)(i + 4 * k + j) * stride];
          r[k][j] = __fadd_rn(r[k][j], __fmul_rn(x, x));
        }
    float L[4];
#pragma unroll
    for (int j = 0; j < 4; j++) {
      float t01 = __fadd_rn(r[0][j], r[1][j]);
      float t23 = __fadd_rn(r[2][j], r[3][j]);
      float t45 = __fadd_rn(r[4][j], r[5][j]);
      float t67 = __fadd_rn(r[6][j], r[7][j]);
      L[j] = __fadd_rn(__fadd_rn(t01, t23), __fadd_rn(t45, t67));
    }
    B[blk] = __fadd_rn(__fadd_rn(L[0], L[1]), __fadd_rn(L[2], L[3]));
  }
  return __fadd_rn(__fadd_rn(B[0], B[1]), __fadd_rn(B[2], B[3]));
}

// ---------------- K0: row squared-norms (np-replicated) ----------------
__global__ __launch_bounds__(256) void k_sq(const float* __restrict__ Z,
                                            const float* __restrict__ ZP,
                                            const float* __restrict__ CB,
                                            float* __restrict__ xxZ,
                                            float* __restrict__ xxP,
                                            float* __restrict__ cb2) {
  int gid = blockIdx.x * 256 + threadIdx.x;
  if (gid < NPIX) {
    int b = gid >> 12, hw = gid & 4095;
    xxZ[gid] = np_pairwise_sq512(Z + (size_t)b * Dn * HW + hw, HW);
  } else if (gid < 2 * NPIX) {
    int p = gid - NPIX;
    int b = p >> 12, hw = p & 4095;
    xxP[p] = np_pairwise_sq512(ZP + (size_t)b * Dn * HW + hw, HW);
  } else if (gid < 2 * NPIX + Kn) {
    int k = gid - 2 * NPIX;
    cb2[k] = np_pairwise_sq512(CB + (size_t)k * Dn, 1);
  }
}

// ---- helpers for bf16 MFMA GEMM ----
__device__ inline unsigned short f2bf(float x) {
  unsigned u = __float_as_uint(x);
  u += 0x7fffu + ((u >> 16) & 1u);  // RNE
  return (unsigned short)(u >> 16);
}
__device__ inline unsigned pack2(float a, float b) {
  return (unsigned)f2bf(a) | ((unsigned)f2bf(b) << 16);
}
// swizzled offset (ushort units) into a [128 rows][4 granules x 8 bf16] tile
__device__ inline int aoff(int row, int g) {
  return row * 32 + ((g ^ ((row >> 1) & 3)) << 3);
}

// ---------------- K1: d = fl((xx + cb2) - 2*m), m via bf16 MFMA ----------------
// 1-D grid 4096 = 8 kx * 256 py * 2 z, XCD-contiguous remap. block 256 (4 waves).
__global__ __launch_bounds__(256) void k_gemm_mfma(const float* __restrict__ Z,
                                                   const float* __restrict__ ZP,
                                                   const float* __restrict__ CB,
                                                   const float* __restrict__ cb2,
                                                   const float* __restrict__ xxZ,
                                                   const float* __restrict__ xxP,
                                                   float* __restrict__ out) {
  __shared__ __align__(16) unsigned short Abf[128 * 32];
  __shared__ __align__(16) unsigned short Bbf[128 * 32];
  __shared__ float xs[128];
  __shared__ float c2s[128];

  const int bid = blockIdx.x;
  const int l = (bid & 7) * 512 + (bid >> 3);   // 8 kx of one py adjacent on one XCD
  const int kx = l & 7;
  const int py = (l >> 3) & 255;
  const int zz = l >> 11;
  const float* A = zz ? ZP : Z;
  const float* xx = zz ? xxP : xxZ;
  float* S = out + (zz ? OFF_PPRB : OFF_PROB);
  const int k0 = kx * 128;
  const int p0g = py * 128;
  const int bb = p0g >> 12, hw0 = p0g & 4095;
  const float* Ab = A + (size_t)bb * (Dn * HW) + hw0;  // + c*HW + p
  const int tid = threadIdx.x;
  if (tid < 128) xs[tid] = xx[p0g + tid];
  else c2s[tid - 128] = cb2[k0 + tid - 128];

  const int pr = tid & 127;   // row owned for staging (p for A, k for B)
  const int gs = tid >> 7;    // granule selector: handles {gs, gs+2}
  const int lane = tid & 63;
  const int wave = tid >> 6;
  const int wm = wave & 1, wn = wave >> 1;
  const int fr = lane & 15, fg = lane >> 4;
  const float* Bb = CB + (size_t)(k0 + pr) * Dn;

  f32x4 acc[4][4] = {};

  for (int c0 = 0; c0 < Dn; c0 += 32) {
#pragma unroll
    for (int gg = 0; gg < 2; gg++) {
      const int g = gs + gg * 2;
      // A: 8 scalar f32 (coalesced across lanes in p), cvt, one b128 write
      float v[8];
#pragma unroll
      for (int j = 0; j < 8; j++)
        v[j] = Ab[(size_t)(c0 + g * 8 + j) * HW + pr];
      uint4 ua;
      ua.x = pack2(v[0], v[1]); ua.y = pack2(v[2], v[3]);
      ua.z = pack2(v[4], v[5]); ua.w = pack2(v[6], v[7]);
      *(uint4*)&Abf[aoff(pr, g)] = ua;
      // B: 2 float4 (contiguous in c), cvt, one b128 write
      const float4* bp = (const float4*)(Bb + c0 + g * 8);
      float4 b0 = bp[0], b1 = bp[1];
      uint4 ub;
      ub.x = pack2(b0.x, b0.y); ub.y = pack2(b0.z, b0.w);
      ub.z = pack2(b1.x, b1.y); ub.w = pack2(b1.z, b1.w);
      *(uint4*)&Bbf[aoff(pr, g)] = ub;
    }
    __syncthreads();
    short8v af[4], bf[4];
#pragma unroll
    for (int m = 0; m < 4; m++)
      af[m] = *(const short8v*)&Abf[aoff(wm * 64 + m * 16 + fr, fg)];
#pragma unroll
    for (int n = 0; n < 4; n++)
      bf[n] = *(const short8v*)&Bbf[aoff(wn * 64 + n * 16 + fr, fg)];
#pragma unroll
    for (int m = 0; m < 4; m++)
#pragma unroll
      for (int n = 0; n < 4; n++)
        acc[m][n] = __builtin_amdgcn_mfma_f32_16x16x32_bf16(af[m], bf[n], acc[m][n], 0, 0, 0);
    __syncthreads();
  }

  // epilogue: d = fl(fl(xx+cb2) - 2*m); C/D layout col=lane&15, row=(lane>>4)*4+reg
  const int ro = fg * 4;
#pragma unroll
  for (int m = 0; m < 4; m++) {
    const int pl = wm * 64 + m * 16 + ro;
#pragma unroll
    for (int n = 0; n < 4; n++) {
      const int kl = wn * 64 + n * 16 + fr;
      const float c2 = c2s[kl];
      const size_t gbase = (size_t)(p0g + pl) * Kn + (k0 + kl);
#pragma unroll
      for (int r = 0; r < 4; r++) {
        float T1 = __fadd_rn(xs[pl + r], c2);
        float d = __fsub_rn(T1, __fmul_rn(2.0f, acc[m][n][r]));
        S[gbase + (size_t)r * Kn] = d;
      }
    }
  }
}

// ---------------- K2: argmin (margin + exact f32 refine) + softmax ----------------
__global__ __launch_bounds__(256) void k_row(const float* __restrict__ Z,
                                             const float* __restrict__ CB,
                                             const float* __restrict__ cb2,
                                             const float* __restrict__ xxZ,
                                             float* __restrict__ out,
                                             int* __restrict__ widx) {
  const int p = blockIdx.x;
  const int sel = blockIdx.y;
  float* S = out + (sel ? OFF_PPRB : OFF_PROB) + (size_t)p * Kn;
  const int t = threadIdx.x;
  __shared__ float rf[256];
  __shared__ int ri[256];
  __shared__ int clist[64];
  __shared__ int ccount;

  float v[4];
#pragma unroll
  for (int i = 0; i < 4; i++) v[i] = S[t + i * 256];

  float lmin = v[0];
  int lidx = t;
#pragma unroll
  for (int i = 1; i < 4; i++) {
    if (v[i] < lmin) { lmin = v[i]; lidx = t + i * 256; }
  }
  rf[t] = lmin; ri[t] = lidx;
  __syncthreads();
  for (int s = 128; s > 0; s >>= 1) {
    if (t < s) {
      float o = rf[t + s]; int oi = ri[t + s];
      if (o < rf[t] || (o == rf[t] && oi < ri[t])) { rf[t] = o; ri[t] = oi; }
    }
    __syncthreads();
  }
  const float smin = rf[0];
  const int sidx = ri[0];
  __syncthreads();

  // softmax on d_approx (loose tolerance)
  float e[4];
  float ls = 0.f;
#pragma unroll
  for (int i = 0; i < 4; i++) { e[i] = expf(smin - v[i]); ls += e[i]; }
  rf[t] = ls;
  __syncthreads();
  for (int s = 128; s > 0; s >>= 1) {
    if (t < s) rf[t] += rf[t + s];
    __syncthreads();
  }
  const float inv = 1.0f / rf[0];
#pragma unroll
  for (int i = 0; i < 4; i++) S[t + i * 256] = e[i] * inv;

  if (sel) return;

  // ---- argmin refine: candidates within margin of approx min ----
  const float MARGIN = 1e-3f;   // ~50 sigma of the bf16-GEMM d error
  int lc = 0;
#pragma unroll
  for (int i = 0; i < 4; i++) lc += (v[i] <= smin + MARGIN) ? 1 : 0;
  __syncthreads();
  ri[t] = lc;
  __syncthreads();
  for (int s = 128; s > 0; s >>= 1) {
    if (t < s) ri[t] += ri[t + s];
    __syncthreads();
  }
  const int ncand = ri[0];
  __syncthreads();

  int final_idx = sidx;
  if (ncand > 1) {  // block-uniform
    if (t == 0) ccount = 0;
    __syncthreads();
#pragma unroll
    for (int i = 0; i < 4; i++)
      if (v[i] <= smin + MARGIN) {
        int slot = atomicAdd(&ccount, 1);
        if (slot < 64) clist[slot] = t + i * 256;
      }
    __syncthreads();
    const int nc = min(ccount, 64);
    const int bb = p >> 12, hw = p & 4095;
    const float* zr = Z + (size_t)bb * Dn * HW + hw;
    const float z0 = zr[(size_t)t * HW];
    const float z1 = zr[(size_t)(t + 256) * HW];
    const float T0 = xxZ[p];
    float bestd = 1e30f;
    int besti = 0x7fffffff;
    for (int j = 0; j < nc; j++) {
      const int k = clist[j];
      const float* cr = CB + (size_t)k * Dn;
      rf[t] = fmaf(z1, cr[t + 256], __fmul_rn(z0, cr[t]));
      __syncthreads();
      for (int s = 128; s > 0; s >>= 1) {
        if (t < s) rf[t] += rf[t + s];
        __syncthreads();
      }
      const float m = rf[0];
      __syncthreads();
      const float d = __fsub_rn(__fadd_rn(T0, cb2[k]), __fmul_rn(2.0f, m));
      if (d < bestd || (d == bestd && k < besti)) { bestd = d; besti = k; }
    }
    final_idx = besti;
  }
  if (t == 0) {
    out[OFF_IDX + p] = (float)final_idx;
    widx[p] = final_idx;
  }
}

// ---------------- K3: z_q gather + squared-error partials ----------------
__global__ __launch_bounds__(256) void k_zqloss(const float* __restrict__ Z,
                                                const float* __restrict__ CB,
                                                const int* __restrict__ widx,
                                                float* __restrict__ out,
                                                float* __restrict__ partial) {
  __shared__ float red[256];
  const int t = threadIdx.x;
  float ls = 0.f;
  const size_t base = (size_t)blockIdx.x * 4096;
#pragma unroll
  for (int i = 0; i < 16; i++) {
    size_t e = base + (size_t)i * 256 + t;
    int hw = (int)(e & 4095);
    int c = (int)((e >> 12) & 511);
    int bb = (int)(e >> 21);
    int p = (bb << 12) | hw;
    float zv = Z[e];
    float qv = CB[(size_t)widx[p] * Dn + c];
    out[e] = qv;
    float d = zv - qv;
    ls = fmaf(d, d, ls);
  }
  red[t] = ls;
  __syncthreads();
  for (int s = 128; s > 0; s >>= 1) {
    if (t < s) red[t] += red[t + s];
    __syncthreads();
  }
  if (t == 0) partial[blockIdx.x] = red[0];
}

// ---------------- K4: finalize q_loss ----------------
__global__ __launch_bounds__(256) void k_loss(const float* __restrict__ partial,
                                              float* __restrict__ out) {
  __shared__ float red[256];
  const int t = threadIdx.x;
  float s = 0.f;
  for (int i = t; i < 4096; i += 256) s += partial[i];
  red[t] = s;
  __syncthreads();
  for (int k = 128; k > 0; k >>= 1) {
    if (t < k) red[t] += red[t + k];
    __syncthreads();
  }
  if (t == 0) out[OFF_LOSS] = red[0] * (1.25f / 16777216.0f);
}

extern "C" void kernel_launch(void* const* d_in, const int* in_sizes, int n_in,
                              void* d_out, int out_size, void* d_ws, size_t ws_size,
                              hipStream_t stream) {
  const float* Z = (const float*)d_in[0];
  const float* ZP = (const float*)d_in[1];
  const float* CB = (const float*)d_in[2];
  float* out = (float*)d_out;
  float* cb2 = (float*)d_ws;                                       // 1024 f32
  float* xxZ = (float*)((char*)d_ws + 4096);                       // 32768 f32
  float* xxP = (float*)((char*)d_ws + 4096 + 131072);              // 32768 f32
  int* widx = (int*)((char*)d_ws + 4096 + 262144);                 // 32768 i32
  float* partial = (float*)((char*)d_ws + 4096 + 262144 + 131072); // 4096 f32

  k_sq<<<dim3((2 * NPIX + Kn + 255) / 256), 256, 0, stream>>>(Z, ZP, CB, xxZ, xxP, cb2);
  k_gemm_mfma<<<dim3(4096), 256, 0, stream>>>(Z, ZP, CB, cb2, xxZ, xxP, out);
  k_row<<<dim3(NPIX, 2), 256, 0, stream>>>(Z, CB, cb2, xxZ, out, widx);
  k_zqloss<<<dim3(4096), 256, 0, stream>>>(Z, CB, widx, out, partial);
  k_loss<<<dim3(1), 256, 0, stream>>>(partial, out);
}

// Round 4
// 638.529 us; speedup vs baseline: 1.7802x; 1.0477x over previous
//
#include <hip/hip_runtime.h>
#include <hip/hip_bf16.h>

static constexpr int Bn = 8, Dn = 512, Hn = 64, Wn = 64, Kn = 1024;
static constexpr int HW = Hn * Wn;            // 4096
static constexpr int NPIX = Bn * HW;          // 32768
static constexpr size_t OFF_LOSS = (size_t)Bn * Dn * HW;          // 16777216
static constexpr size_t OFF_PROB = OFF_LOSS + 1;                   // 16777217
static constexpr size_t OFF_IDX  = OFF_PROB + (size_t)NPIX * Kn;   // 50331649
static constexpr size_t OFF_PPRB = OFF_IDX + NPIX;                 // 50364417

typedef __attribute__((ext_vector_type(8))) short short8v;
typedef __attribute__((ext_vector_type(4))) float f32x4;
typedef unsigned long long ull;

// workspace layout (bytes)
static constexpr size_t WS_CB2    = 0;        // 1024 f32
static constexpr size_t WS_XXZ    = 4096;     // 32768 f32
static constexpr size_t WS_WIDX   = 135168;   // 32768 i32
static constexpr size_t WS_NFLAG  = 266240;   // 1 i32
static constexpr size_t WS_FLAGS  = 267264;   // 32768 i32 (packed p<<10|k)
static constexpr size_t WS_REFMIN = 398336;   // 32768 u64
static constexpr size_t WS_PART   = 660480;   // 4096 f32
static constexpr size_t WS_CBBF   = 676864;   // 1024*512 bf16 (1 MB)

#define MARGIN 1e-3f

// ---- numpy pairwise-sum replica for n=512 f32 row of squares ----
__device__ float np_pairwise_sq512(const float* __restrict__ base, int stride) {
  float B[4];
#pragma unroll
  for (int blk = 0; blk < 4; blk++) {
    const float* a = base + (size_t)blk * 128 * stride;
    float r[8][4];
#pragma unroll
    for (int k = 0; k < 8; k++)
#pragma unroll
      for (int j = 0; j < 4; j++) {
        float x = a[(size_t)(4 * k + j) * stride];
        r[k][j] = __fmul_rn(x, x);
      }
#pragma unroll
    for (int i = 32; i < 128; i += 32)
#pragma unroll
      for (int k = 0; k < 8; k++)
#pragma unroll
        for (int j = 0; j < 4; j++) {
          float x = a[(size_t)(i + 4 * k + j) * stride];
          r[k][j] = __fadd_rn(r[k][j], __fmul_rn(x, x));
        }
    float L[4];
#pragma unroll
    for (int j = 0; j < 4; j++) {
      float t01 = __fadd_rn(r[0][j], r[1][j]);
      float t23 = __fadd_rn(r[2][j], r[3][j]);
      float t45 = __fadd_rn(r[4][j], r[5][j]);
      float t67 = __fadd_rn(r[6][j], r[7][j]);
      L[j] = __fadd_rn(__fadd_rn(t01, t23), __fadd_rn(t45, t67));
    }
    B[blk] = __fadd_rn(__fadd_rn(L[0], L[1]), __fadd_rn(L[2], L[3]));
  }
  return __fadd_rn(__fadd_rn(B[0], B[1]), __fadd_rn(B[2], B[3]));
}

// ---------------- K0a: np-replica norms (xxZ for refine, cb2) ----------------
__global__ __launch_bounds__(256) void k_sq(const float* __restrict__ Z,
                                            const float* __restrict__ CB,
                                            float* __restrict__ xxZ,
                                            float* __restrict__ cb2) {
  int gid = blockIdx.x * 256 + threadIdx.x;
  if (gid < NPIX) {
    int b = gid >> 12, hw = gid & 4095;
    xxZ[gid] = np_pairwise_sq512(Z + (size_t)b * Dn * HW + hw, HW);
  } else if (gid < NPIX + Kn) {
    int k = gid - NPIX;
    cb2[k] = np_pairwise_sq512(CB + (size_t)k * Dn, 1);
  }
}

// ---------------- K0b: CB->bf16, init refmin + nflag ----------------
__global__ __launch_bounds__(256) void k_cvt(const float* __restrict__ CB,
                                             unsigned short* __restrict__ CBbf,
                                             ull* __restrict__ refmin,
                                             int* __restrict__ nflag) {
  int gid = blockIdx.x * 256 + threadIdx.x;   // grid 1024*256 = 262144
  float2 f = *(const float2*)(CB + (size_t)gid * 2);
  union { __hip_bfloat162 h; unsigned u; } cv;
  cv.h = __float22bfloat162_rn(f);
  ((unsigned*)CBbf)[gid] = cv.u;
  if (gid < NPIX) refmin[gid] = ~0ull;
  if (gid == 0) *nflag = 0;
}

// ---------------- K1: fused GEMM + softmax + argmin/flag ----------------
// grid (1024, 2), block 512 (8 waves). Block: 32 p-rows x full K=1024.
__global__ __launch_bounds__(512) void k_fused(const float* __restrict__ Z,
                                               const float* __restrict__ ZP,
                                               const unsigned short* __restrict__ CBbf,
                                               const float* __restrict__ cb2,
                                               float* __restrict__ out,
                                               int* __restrict__ widx,
                                               int* __restrict__ nflag,
                                               int* __restrict__ flags) {
  const int py = blockIdx.x;
  const int zz = blockIdx.y;
  const int p0 = py * 32;
  const float* A = zz ? ZP : Z;
  float* S = out + (zz ? OFF_PPRB : OFF_PROB);
  const int bb = p0 >> 12, hw0 = p0 & 4095;
  const float* Ab = A + (size_t)bb * (Dn * HW) + hw0;  // + c*HW + p_local
  const int tid = threadIdx.x;
  const int lane = tid & 63, w = tid >> 6;
  const int fr = lane & 15, fg = lane >> 4;

  const unsigned short* Bb = CBbf + ((size_t)(w * 128 + fr) * 512) + fg * 8;
  const float* Abase = Ab + (size_t)(fg * 8) * HW + fr;  // + (c0+j)*HW + m*16

  f32x4 acc[2][8] = {};

#pragma unroll
  for (int c0 = 0; c0 < 512; c0 += 32) {
    short8v af[2];
#pragma unroll
    for (int m = 0; m < 2; m++) {
      float v[8];
#pragma unroll
      for (int j = 0; j < 8; j++)
        v[j] = Abase[(size_t)(c0 + j) * HW + m * 16];
      union { short8v s; unsigned u[4]; } cv;
#pragma unroll
      for (int q = 0; q < 4; q++) {
        union { __hip_bfloat162 h; unsigned u; } t;
        t.h = __float22bfloat162_rn(make_float2(v[2 * q], v[2 * q + 1]));
        cv.u[q] = t.u;
      }
      af[m] = cv.s;
    }
    short8v bfv[8];
#pragma unroll
    for (int n = 0; n < 8; n++)
      bfv[n] = *(const short8v*)(Bb + c0 + n * 8192);
#pragma unroll
    for (int m = 0; m < 2; m++)
#pragma unroll
      for (int n = 0; n < 8; n++)
        acc[m][n] = __builtin_amdgcn_mfma_f32_16x16x32_bf16(af[m], bfv[n], acc[m][n], 0, 0, 0);
  }

  // s = cb2[k] - 2*m  (xx cancels in softmax/argmin; exact path is in refine)
  float c2[8];
#pragma unroll
  for (int n = 0; n < 8; n++) c2[n] = cb2[w * 128 + n * 16 + fr];
#pragma unroll
  for (int m = 0; m < 2; m++)
#pragma unroll
    for (int n = 0; n < 8; n++)
#pragma unroll
      for (int r = 0; r < 4; r++)
        acc[m][n][r] = __fsub_rn(c2[n], __fmul_rn(2.0f, acc[m][n][r]));

  __shared__ float redv[8][32];
  __shared__ int   redi[8][32];
  __shared__ float reds[8][32];
  __shared__ int   redc[8][32];
  __shared__ float rowmin_s[32];
  __shared__ int   rowidx_s[32];
  __shared__ float rowinv_s[32];
  __shared__ int   rowcnt_s[32];
  __shared__ int pcnt, pbase;
  __shared__ int pbuf[512];
  if (tid == 0) pcnt = 0;

  // phase 1: lexicographic (val, idx) row-min
#pragma unroll
  for (int m = 0; m < 2; m++)
#pragma unroll
    for (int r = 0; r < 4; r++) {
      float bv = acc[m][0][r];
      int bi = w * 128 + fr;
#pragma unroll
      for (int n = 1; n < 8; n++) {
        float x = acc[m][n][r];
        int xi = w * 128 + n * 16 + fr;
        if (x < bv || (x == bv && xi < bi)) { bv = x; bi = xi; }
      }
#pragma unroll
      for (int d = 1; d < 16; d <<= 1) {
        float ov = __shfl_xor(bv, d, 64);
        int oi = __shfl_xor(bi, d, 64);
        if (ov < bv || (ov == bv && oi < bi)) { bv = ov; bi = oi; }
      }
      if (fr == 0) {
        int row = m * 16 + fg * 4 + r;
        redv[w][row] = bv; redi[w][row] = bi;
      }
    }
  __syncthreads();
  if (tid < 32) {
    float bv = redv[0][tid]; int bi = redi[0][tid];
    for (int ww = 1; ww < 8; ww++) {
      float ov = redv[ww][tid]; int oi = redi[ww][tid];
      if (ov < bv || (ov == bv && oi < bi)) { bv = ov; bi = oi; }
    }
    rowmin_s[tid] = bv; rowidx_s[tid] = bi;
  }
  __syncthreads();

  // phase 2: exp-sum + margin count
#pragma unroll
  for (int m = 0; m < 2; m++)
#pragma unroll
    for (int r = 0; r < 4; r++) {
      const int row = m * 16 + fg * 4 + r;
      const float rm = rowmin_s[row];
      float sum = 0.f; int cnt = 0;
#pragma unroll
      for (int n = 0; n < 8; n++) {
        float s = acc[m][n][r];
        sum += __expf(rm - s);
        cnt += (s <= rm + MARGIN) ? 1 : 0;
      }
#pragma unroll
      for (int d = 1; d < 16; d <<= 1) {
        sum += __shfl_xor(sum, d, 64);
        cnt += __shfl_xor(cnt, d, 64);
      }
      if (fr == 0) { reds[w][row] = sum; redc[w][row] = cnt; }
    }
  __syncthreads();
  if (tid < 32) {
    float sm = 0.f; int ct = 0;
    for (int ww = 0; ww < 8; ww++) { sm += reds[ww][tid]; ct += redc[ww][tid]; }
    rowinv_s[tid] = 1.0f / sm;
    rowcnt_s[tid] = ct;
  }
  __syncthreads();

  // phase 3: store probs + append multi-candidate pairs
#pragma unroll
  for (int m = 0; m < 2; m++)
#pragma unroll
    for (int r = 0; r < 4; r++) {
      const int row = m * 16 + fg * 4 + r;
      const float rm = rowmin_s[row];
      const float inv = rowinv_s[row];
      const bool multi = (rowcnt_s[row] > 1);
      float* Sp = S + (size_t)(p0 + row) * Kn + w * 128 + fr;
#pragma unroll
      for (int n = 0; n < 8; n++) {
        float s = acc[m][n][r];
        Sp[n * 16] = __expf(rm - s) * inv;
        if (zz == 0 && multi && s <= rm + MARGIN) {
          int slot = atomicAdd(&pcnt, 1);
          if (slot < 512) pbuf[slot] = ((p0 + row) << 10) | (w * 128 + n * 16 + fr);
        }
      }
    }
  // single-candidate rows: argmin settled
  if (zz == 0 && tid < 32 && rowcnt_s[tid] == 1) {
    widx[p0 + tid] = rowidx_s[tid];
    out[OFF_IDX + p0 + tid] = (float)rowidx_s[tid];
  }
  __syncthreads();
  if (zz == 0) {
    if (tid == 0) pbase = atomicAdd(nflag, min(pcnt, 512));
    __syncthreads();
    int np = min(pcnt, 512);
    if (tid < np) flags[pbase + tid] = pbuf[tid];
  }
}

// ---------------- K2: exact seq-fma recompute per flagged (p,k) pair ----------------
__global__ __launch_bounds__(256) void k_refine(const float* __restrict__ Z,
                                                const float* __restrict__ CB,
                                                const float* __restrict__ cb2,
                                                const float* __restrict__ xxZ,
                                                const int* __restrict__ flags,
                                                const int* __restrict__ nflag,
                                                ull* __restrict__ refmin) {
  const int np = min(*nflag, NPIX);
  for (int i = blockIdx.x * 256 + threadIdx.x; i < np; i += 256 * 256) {
    int pk = flags[i];
    int p = pk >> 10, k = pk & 1023;
    const float* zr = Z + (size_t)(p >> 12) * (Dn * HW) + (p & 4095);
    const float* cr = CB + (size_t)k * Dn;
    float m = 0.f;
    for (int c = 0; c < Dn; c++)
      m = fmaf(zr[(size_t)c * HW], cr[c], m);   // sequential, np-matching (round-2-proven)
    float d = __fsub_rn(__fadd_rn(xxZ[p], cb2[k]), __fmul_rn(2.0f, m));
    ull key = ((ull)__float_as_uint(d) << 32) | (unsigned)k;  // d>0; ties -> lowest k
    atomicMin(refmin + p, key);
  }
}

// ---------------- K3: write back refined argmin ----------------
__global__ __launch_bounds__(256) void k_refidx(const int* __restrict__ flags,
                                                const int* __restrict__ nflag,
                                                const ull* __restrict__ refmin,
                                                int* __restrict__ widx,
                                                float* __restrict__ out) {
  const int np = min(*nflag, NPIX);
  for (int i = blockIdx.x * 256 + threadIdx.x; i < np; i += 64 * 256) {
    int p = flags[i] >> 10;
    int k = (int)(refmin[p] & 0x3ffu);
    widx[p] = k;
    out[OFF_IDX + p] = (float)k;
  }
}

// ---------------- K4: z_q gather + squared-error partials ----------------
__global__ __launch_bounds__(256) void k_zqloss(const float* __restrict__ Z,
                                                const float* __restrict__ CB,
                                                const int* __restrict__ widx,
                                                float* __restrict__ out,
                                                float* __restrict__ partial) {
  __shared__ float red[256];
  const int t = threadIdx.x;
  float ls = 0.f;
  const size_t base = (size_t)blockIdx.x * 4096;
#pragma unroll
  for (int i = 0; i < 16; i++) {
    size_t e = base + (size_t)i * 256 + t;
    int hw = (int)(e & 4095);
    int c = (int)((e >> 12) & 511);
    int bb = (int)(e >> 21);
    int p = (bb << 12) | hw;
    float zv = Z[e];
    float qv = CB[(size_t)widx[p] * Dn + c];
    out[e] = qv;
    float d = zv - qv;
    ls = fmaf(d, d, ls);
  }
  red[t] = ls;
  __syncthreads();
  for (int s = 128; s > 0; s >>= 1) {
    if (t < s) red[t] += red[t + s];
    __syncthreads();
  }
  if (t == 0) partial[blockIdx.x] = red[0];
}

// ---------------- K5: finalize q_loss ----------------
__global__ __launch_bounds__(256) void k_loss(const float* __restrict__ partial,
                                              float* __restrict__ out) {
  __shared__ float red[256];
  const int t = threadIdx.x;
  float s = 0.f;
  for (int i = t; i < 4096; i += 256) s += partial[i];
  red[t] = s;
  __syncthreads();
  for (int k = 128; k > 0; k >>= 1) {
    if (t < k) red[t] += red[t + k];
    __syncthreads();
  }
  if (t == 0) out[OFF_LOSS] = red[0] * (1.25f / 16777216.0f);
}

extern "C" void kernel_launch(void* const* d_in, const int* in_sizes, int n_in,
                              void* d_out, int out_size, void* d_ws, size_t ws_size,
                              hipStream_t stream) {
  const float* Z = (const float*)d_in[0];
  const float* ZP = (const float*)d_in[1];
  const float* CB = (const float*)d_in[2];
  float* out = (float*)d_out;
  char* ws = (char*)d_ws;
  float* cb2 = (float*)(ws + WS_CB2);
  float* xxZ = (float*)(ws + WS_XXZ);
  int* widx = (int*)(ws + WS_WIDX);
  int* nflag = (int*)(ws + WS_NFLAG);
  int* flags = (int*)(ws + WS_FLAGS);
  ull* refmin = (ull*)(ws + WS_REFMIN);
  float* partial = (float*)(ws + WS_PART);
  unsigned short* CBbf = (unsigned short*)(ws + WS_CBBF);

  k_sq<<<dim3((NPIX + Kn + 255) / 256), 256, 0, stream>>>(Z, CB, xxZ, cb2);
  k_cvt<<<dim3(1024), 256, 0, stream>>>(CB, CBbf, refmin, nflag);
  k_fused<<<dim3(1024, 2), 512, 0, stream>>>(Z, ZP, CBbf, cb2, out, widx, nflag, flags);
  k_refine<<<dim3(256), 256, 0, stream>>>(Z, CB, cb2, xxZ, flags, nflag, refmin);
  k_refidx<<<dim3(64), 256, 0, stream>>>(flags, nflag, refmin, widx, out);
  k_zqloss<<<dim3(4096), 256, 0, stream>>>(Z, CB, widx, out, partial);
  k_loss<<<dim3(1), 256, 0, stream>>>(partial, out);
}